// Round 2
// baseline (575.328 us; speedup 1.0000x reference)
//
#include <hip/hip_runtime.h>
#include <hip/hip_cooperative_groups.h>
#include <math.h>

namespace cg = cooperative_groups;

#define NN 4096
#define NFEAT 512
#define NHID 60
#define NCLASS 4
#define CAP 96      // per-row nnz capacity (mean ~8.2, statistical max ~22)
#define GSTRIDE 64  // padded hidden-state row stride

struct Params {
    const float *x, *adj, *P, *W1, *b1, *W2, *b2, *W3, *b3, *lw, *lb;
    float *out;
    float *dcol; int *cnt; int *cols; float *vals; float *bufA; float *bufB;
};

// ---- scan sub_adj -> per-row lists + column sums (dcol starts at 0; +1 self-loop folded later)
__device__ __forceinline__ void scan_phase(const Params& p, int gtid, int nthreads) {
    const int nvec = (NN * NN) / 4;
    for (int v = gtid; v < nvec; v += nthreads) {
        const float4 a = ((const float4*)p.adj)[v];
        if (a.x == 0.f && a.y == 0.f && a.z == 0.f && a.w == 0.f) continue;
        const int e0 = v * 4;
        const float av[4] = {a.x, a.y, a.z, a.w};
        #pragma unroll
        for (int q = 0; q < 4; ++q) {
            if (av[q] != 0.f) {
                const int e = e0 + q;
                const int i = e >> 12;
                const int j = e & (NN - 1);
                const int hi = i > j ? i : j;
                const int lo = i > j ? j : i;
                const float pv = p.P[((hi * (hi + 1)) >> 1) + lo];
                const float s = av[q] / (1.f + __expf(-pv));   // sigmoid * adj
                atomicAdd(&p.dcol[j], s);
                const int pos = atomicAdd(&p.cnt[i], 1);
                if (pos < CAP) { p.cols[i * CAP + pos] = j; p.vals[i * CAP + pos] = s; }
            }
        }
    }
}

// ---- G1 = x @ W1 (4096x512 @ 512x60), 4 rows/block, K split across 4 waves
__device__ __forceinline__ void xw_phase(const Params& p, float* xst, float* part,
                                         int w, int lane, int tid) {
    for (int bi = blockIdx.x; bi < NN / 4; bi += gridDim.x) {
        const int row0 = bi * 4;
        for (int f = tid; f < 4 * NFEAT; f += 256) {
            const int r = f >> 9, k = f & (NFEAT - 1);
            xst[k * 4 + r] = p.x[(row0 + r) * NFEAT + k];   // transposed stage
        }
        __syncthreads();
        const int c = lane < NHID ? lane : 0;
        float a0 = 0.f, a1 = 0.f, a2 = 0.f, a3 = 0.f;
        const int k0 = w * (NFEAT / 4);
        for (int k = k0; k < k0 + NFEAT / 4; ++k) {
            const float wv = p.W1[k * NHID + c];             // coalesced, L2
            const float4 xv = *(const float4*)&xst[k * 4];   // LDS broadcast
            a0 = fmaf(xv.x, wv, a0); a1 = fmaf(xv.y, wv, a1);
            a2 = fmaf(xv.z, wv, a2); a3 = fmaf(xv.w, wv, a3);
        }
        part[(w * 4 + 0) * 64 + lane] = a0;
        part[(w * 4 + 1) * 64 + lane] = a1;
        part[(w * 4 + 2) * 64 + lane] = a2;
        part[(w * 4 + 3) * 64 + lane] = a3;
        __syncthreads();
        // wave w reduces row w over the 4 K-partials
        const float o = part[(0 * 4 + w) * 64 + lane] + part[(1 * 4 + w) * 64 + lane]
                      + part[(2 * 4 + w) * 64 + lane] + part[(3 * 4 + w) * 64 + lane];
        p.bufA[(row0 + w) * GSTRIDE + lane] = (lane < NHID) ? o : 0.f;
        __syncthreads();   // protect xst/part if the block loops again
    }
}

// ---- h = act(spmm(gin)+bias); gout = h @ W (60x60). One row per wave.
__device__ __forceinline__ void layer_phase(const Params& p, const float* gin, float* gout,
                                            const float* bias, const float* W, bool relu,
                                            float* hs, int w, int lane) {
    for (int bi = blockIdx.x; bi < NN / 4; bi += gridDim.x) {
        const int i = bi * 4 + w;
        const float di = rsqrtf(1.f + p.dcol[i]);
        const int nn = min(p.cnt[i], CAP);
        float acc = gin[i * GSTRIDE + lane] * di;     // self-loop term
        for (int e = 0; e < nn; ++e) {
            const int j = p.cols[i * CAP + e];
            const float f = p.vals[i * CAP + e] * rsqrtf(1.f + p.dcol[j]);
            acc = fmaf(f, gin[j * GSTRIDE + lane], acc);   // coalesced 256B row gather
        }
        acc *= di;
        if (lane < NHID) {
            acc += bias[lane];
            if (relu) acc = fmaxf(acc, 0.f);
        } else acc = 0.f;
        hs[w * 64 + lane] = acc;
        __syncthreads();
        const int c = lane < NHID ? lane : 0;
        float o = 0.f;
        for (int k = 0; k < NHID; ++k)
            o = fmaf(hs[w * 64 + k], W[k * NHID + c], o);   // hs = LDS broadcast (free)
        gout[i * GSTRIDE + lane] = (lane < NHID) ? o : 0.f;
        __syncthreads();
    }
}

// ---- h3 = spmm+b3; logits = h3@lin_w+lin_b; log_softmax over 4 classes
__device__ __forceinline__ void final_phase(const Params& p, const float* gin,
                                            float* hs, int w, int lane) {
    for (int bi = blockIdx.x; bi < NN / 4; bi += gridDim.x) {
        const int i = bi * 4 + w;
        const float di = rsqrtf(1.f + p.dcol[i]);
        const int nn = min(p.cnt[i], CAP);
        float acc = gin[i * GSTRIDE + lane] * di;
        for (int e = 0; e < nn; ++e) {
            const int j = p.cols[i * CAP + e];
            const float f = p.vals[i * CAP + e] * rsqrtf(1.f + p.dcol[j]);
            acc = fmaf(f, gin[j * GSTRIDE + lane], acc);
        }
        acc *= di;
        hs[w * 64 + lane] = (lane < NHID) ? acc + p.b3[lane] : 0.f;
        __syncthreads();
        if (lane < NCLASS) {
            float o = p.lb[lane];
            for (int k = 0; k < NHID; ++k)
                o = fmaf(hs[w * 64 + k], p.lw[k * NCLASS + lane], o);
            float m = fmaxf(o, __shfl_xor(o, 1));
            m = fmaxf(m, __shfl_xor(m, 2));
            const float ex = __expf(o - m);
            float ssum = ex + __shfl_xor(ex, 1);
            ssum += __shfl_xor(ssum, 2);
            p.out[i * NCLASS + lane] = o - m - __logf(ssum);
        }
        __syncthreads();
    }
}

__global__ __launch_bounds__(256, 4) void k_fused(Params p) {
    __shared__ float smem[2048 + 1024];   // xst(8KB) + part(4KB); layers reuse smem[0..255]
    cg::grid_group grid = cg::this_grid();
    const int tid = threadIdx.x;
    const int w = tid >> 6, lane = tid & 63;
    const int gtid = blockIdx.x * 256 + tid;
    const int nthreads = gridDim.x * 256;

    // Phase 0: scan (HBM-bound) + x@W1 (VALU-bound), order alternated per block
    // so both pipe types are resident on each CU simultaneously (m114 overlap).
    if (blockIdx.x & 1) {
        scan_phase(p, gtid, nthreads);
        xw_phase(p, smem, smem + 2048, w, lane, tid);
    } else {
        xw_phase(p, smem, smem + 2048, w, lane, tid);
        scan_phase(p, gtid, nthreads);
    }
    __threadfence();
    grid.sync();

    layer_phase(p, p.bufA, p.bufB, p.b1, p.W2, true, smem, w, lane);
    __threadfence();
    grid.sync();

    layer_phase(p, p.bufB, p.bufA, p.b2, p.W3, true, smem, w, lane);
    __threadfence();
    grid.sync();

    final_phase(p, p.bufA, smem, w, lane);
}

extern "C" void kernel_launch(void* const* d_in, const int* in_sizes, int n_in,
                              void* d_out, int out_size, void* d_ws, size_t ws_size,
                              hipStream_t stream) {
    Params prm;
    prm.x  = (const float*)d_in[0];   // 4096 x 512
    prm.adj = (const float*)d_in[1];  // 4096 x 4096
    prm.P  = (const float*)d_in[2];   // 8390656
    prm.W1 = (const float*)d_in[3];   // 512 x 60
    prm.b1 = (const float*)d_in[4];
    prm.W2 = (const float*)d_in[5];   // 60 x 60
    prm.b2 = (const float*)d_in[6];
    prm.W3 = (const float*)d_in[7];   // 60 x 60
    prm.b3 = (const float*)d_in[8];
    prm.lw = (const float*)d_in[9];   // 60 x 4
    prm.lb = (const float*)d_in[10];
    prm.out = (float*)d_out;          // 4096 x 4

    char* ws = (char*)d_ws;
    prm.dcol = (float*)ws;                              // 16 KiB (zeroed)
    prm.cnt  = (int*)(ws + 16384);                      // 16 KiB (zeroed)
    prm.cols = (int*)(ws + 32768);                      // 1.5 MiB
    prm.vals = (float*)(ws + 32768 + 1572864);          // 1.5 MiB
    prm.bufA = (float*)(ws + 32768 + 2 * 1572864);              // 1 MiB
    prm.bufB = (float*)(ws + 32768 + 2 * 1572864 + 1048576);    // 1 MiB

    hipMemsetAsync(ws, 0, 32768, stream);   // zero dcol + cnt

    // co-residency-safe grid for cooperative launch
    int dev = 0, numCU = 256, q = 0, maxPerCU = 4;
    hipGetDevice(&dev);
    hipDeviceGetAttribute(&numCU, hipDeviceAttributeMultiprocessorCount, dev);
    if (hipOccupancyMaxActiveBlocksPerMultiprocessor(&q, k_fused, 256, 0) == hipSuccess && q > 0)
        maxPerCU = q;
    int nblk = numCU * maxPerCU;
    if (nblk > NN / 4) nblk = NN / 4;

    void* kp[] = { (void*)&prm };
    hipLaunchCooperativeKernel((void*)k_fused, dim3(nblk), dim3(256), kp, 0, stream);
}

// Round 3
// 501.960 us; speedup vs baseline: 1.1462x; 1.1462x over previous
//
#include <hip/hip_runtime.h>
#include <math.h>

#define NN 4096
#define NFEAT 512
#define NHID 60
#define NCLASS 4
#define CAP 96      // per-row nnz capacity (mean ~8.2, statistical max ~22)
#define GSTRIDE 64  // padded hidden-state row stride

struct Params {
    const float *x, *adj, *P, *W1, *b1, *W2, *b2, *W3, *b3, *lw, *lb;
    float *out;
    float *dcol; int *cnt; int *cols; float *vals; float *bufA; float *bufB;
    int *bar_cnt; int *bar_gen;
};

// ---- lightweight monotonic grid barrier (agent scope, no cg) --------------
// count is never reset: barrier n waits for count == n * gridDim.x.
__device__ __forceinline__ void grid_barrier(int* cnt_, int* gen_, int bar_no) {
    __syncthreads();
    if (threadIdx.x == 0) {
        __threadfence();   // release: push this block's writes to device scope
        const int target = bar_no * (int)gridDim.x;
        const int a = __hip_atomic_fetch_add(cnt_, 1, __ATOMIC_RELAXED,
                                             __HIP_MEMORY_SCOPE_AGENT) + 1;
        if (a == target) {
            __hip_atomic_store(gen_, bar_no, __ATOMIC_RELAXED,
                               __HIP_MEMORY_SCOPE_AGENT);
        } else {
            while (__hip_atomic_load(gen_, __ATOMIC_RELAXED,
                                     __HIP_MEMORY_SCOPE_AGENT) < bar_no)
                __builtin_amdgcn_s_sleep(4);
        }
        __threadfence();   // acquire: invalidate stale lines before next phase
    }
    __syncthreads();
}

// ---- scan sub_adj -> per-row lists + column sums --------------------------
__device__ __forceinline__ void process_vec(const Params& p, float4 a, int v) {
    if (a.x == 0.f && a.y == 0.f && a.z == 0.f && a.w == 0.f) return;
    const float av[4] = {a.x, a.y, a.z, a.w};
    const int e0 = v * 4;
    #pragma unroll
    for (int q = 0; q < 4; ++q) {
        if (av[q] != 0.f) {
            const int e = e0 + q;
            const int i = e >> 12;
            const int j = e & (NN - 1);
            const int hi = i > j ? i : j;
            const int lo = i > j ? j : i;
            const float pv = p.P[((hi * (hi + 1)) >> 1) + lo];
            const float s = av[q] / (1.f + __expf(-pv));   // sigmoid * adj
            atomicAdd(&p.dcol[j], s);
            const int pos = atomicAdd(&p.cnt[i], 1);
            if (pos < CAP) { p.cols[i * CAP + pos] = j; p.vals[i * CAP + pos] = s; }
        }
    }
}

__device__ __forceinline__ void scan_phase(const Params& p, int gtid, int nthreads) {
    const int nvec = (NN * NN) / 4;
    const float4* adj4 = (const float4*)p.adj;
    for (int v0 = gtid; v0 < nvec; v0 += 4 * nthreads) {
        const int v1 = v0 + nthreads, v2 = v0 + 2 * nthreads, v3 = v0 + 3 * nthreads;
        // issue all 4 independent loads before any processing (MLP)
        const float4 a0 = adj4[v0];
        const float4 a1 = v1 < nvec ? adj4[v1] : float4{0, 0, 0, 0};
        const float4 a2 = v2 < nvec ? adj4[v2] : float4{0, 0, 0, 0};
        const float4 a3 = v3 < nvec ? adj4[v3] : float4{0, 0, 0, 0};
        process_vec(p, a0, v0);
        if (v1 < nvec) process_vec(p, a1, v1);
        if (v2 < nvec) process_vec(p, a2, v2);
        if (v3 < nvec) process_vec(p, a3, v3);
    }
}

// ---- G1 = x @ W1 (4096x512 @ 512x60): 4 rows/block, K split over 4 waves --
__device__ __forceinline__ void xw_phase(const Params& p, float* part, int w, int lane) {
    const int c = lane < NHID ? lane : 0;
    for (int bi = blockIdx.x; bi < NN / 4; bi += gridDim.x) {
        const int row0 = bi * 4;
        const int k0 = w * (NFEAT / 4);
        const float* x0 = p.x + (row0 + 0) * NFEAT;
        const float* x1 = p.x + (row0 + 1) * NFEAT;
        const float* x2 = p.x + (row0 + 2) * NFEAT;
        const float* x3 = p.x + (row0 + 3) * NFEAT;
        float a0 = 0.f, a1 = 0.f, a2 = 0.f, a3 = 0.f;
        for (int k = k0; k < k0 + NFEAT / 4; k += 4) {
            const float4 xv0 = *(const float4*)(x0 + k);   // wave-uniform 16B
            const float4 xv1 = *(const float4*)(x1 + k);
            const float4 xv2 = *(const float4*)(x2 + k);
            const float4 xv3 = *(const float4*)(x3 + k);
            const float w0 = p.W1[(k + 0) * NHID + c];     // lane-varying, L2-hot
            const float w1 = p.W1[(k + 1) * NHID + c];
            const float w2 = p.W1[(k + 2) * NHID + c];
            const float w3 = p.W1[(k + 3) * NHID + c];
            a0 = fmaf(xv0.x, w0, fmaf(xv0.y, w1, fmaf(xv0.z, w2, fmaf(xv0.w, w3, a0))));
            a1 = fmaf(xv1.x, w0, fmaf(xv1.y, w1, fmaf(xv1.z, w2, fmaf(xv1.w, w3, a1))));
            a2 = fmaf(xv2.x, w0, fmaf(xv2.y, w1, fmaf(xv2.z, w2, fmaf(xv2.w, w3, a2))));
            a3 = fmaf(xv3.x, w0, fmaf(xv3.y, w1, fmaf(xv3.z, w2, fmaf(xv3.w, w3, a3))));
        }
        part[(w * 4 + 0) * 64 + lane] = a0;
        part[(w * 4 + 1) * 64 + lane] = a1;
        part[(w * 4 + 2) * 64 + lane] = a2;
        part[(w * 4 + 3) * 64 + lane] = a3;
        __syncthreads();
        // wave w reduces row w across the 4 K-slices
        const float o = part[(0 * 4 + w) * 64 + lane] + part[(1 * 4 + w) * 64 + lane]
                      + part[(2 * 4 + w) * 64 + lane] + part[(3 * 4 + w) * 64 + lane];
        p.bufA[(row0 + w) * GSTRIDE + lane] = (lane < NHID) ? o : 0.f;
        __syncthreads();
    }
}

// ---- spmm edge accumulation, 4-batched for MLP ----------------------------
__device__ __forceinline__ float spmm_row(const Params& p, const float* gin,
                                          int i, int lane, float di) {
    const int nn = min(p.cnt[i], CAP);
    float acc = gin[i * GSTRIDE + lane] * di;   // self-loop term
    const int4*   c4 = (const int4*)(p.cols + i * CAP);
    const float4* v4 = (const float4*)(p.vals + i * CAP);
    int e = 0;
    for (; e + 4 <= nn; e += 4) {
        const int4   jj = c4[e >> 2];
        const float4 vv = v4[e >> 2];
        const float f0 = vv.x * rsqrtf(1.f + p.dcol[jj.x]);
        const float f1 = vv.y * rsqrtf(1.f + p.dcol[jj.y]);
        const float f2 = vv.z * rsqrtf(1.f + p.dcol[jj.z]);
        const float f3 = vv.w * rsqrtf(1.f + p.dcol[jj.w]);
        const float g0 = gin[jj.x * GSTRIDE + lane];
        const float g1 = gin[jj.y * GSTRIDE + lane];
        const float g2 = gin[jj.z * GSTRIDE + lane];
        const float g3 = gin[jj.w * GSTRIDE + lane];
        acc = fmaf(f0, g0, fmaf(f1, g1, fmaf(f2, g2, fmaf(f3, g3, acc))));
    }
    for (; e < nn; ++e) {
        const int j = p.cols[i * CAP + e];
        const float f = p.vals[i * CAP + e] * rsqrtf(1.f + p.dcol[j]);
        acc = fmaf(f, gin[j * GSTRIDE + lane], acc);
    }
    return acc * di;
}

// ---- h = act(spmm(gin)+bias); gout = h @ W (60x60). One row per wave. -----
__device__ __forceinline__ void layer_phase(const Params& p, const float* gin, float* gout,
                                            const float* bias, const float* W, int relu,
                                            float* hs, int w, int lane) {
    for (int bi = blockIdx.x; bi < NN / 4; bi += gridDim.x) {
        const int i = bi * 4 + w;
        const float di = rsqrtf(1.f + p.dcol[i]);
        float acc = spmm_row(p, gin, i, lane, di);
        float hv = 0.f;
        if (lane < NHID) {
            hv = acc + bias[lane];
            if (relu) hv = fmaxf(hv, 0.f);
        }
        hs[w * 64 + lane] = hv;
        __syncthreads();
        const int c = lane < NHID ? lane : 0;
        float o = 0.f;
        #pragma unroll 4
        for (int k = 0; k < NHID; ++k)
            o = fmaf(hs[w * 64 + k], W[k * NHID + c], o);
        gout[i * GSTRIDE + lane] = (lane < NHID) ? o : 0.f;
        __syncthreads();
    }
}

// ---- h3 = spmm+b3; logits = h3@lin_w+lin_b; log_softmax over 4 classes ----
__device__ __forceinline__ void final_phase(const Params& p, const float* gin,
                                            float* hs, int w, int lane) {
    for (int bi = blockIdx.x; bi < NN / 4; bi += gridDim.x) {
        const int i = bi * 4 + w;
        const float di = rsqrtf(1.f + p.dcol[i]);
        float acc = spmm_row(p, gin, i, lane, di);
        hs[w * 64 + lane] = (lane < NHID) ? acc + p.b3[lane] : 0.f;
        __syncthreads();
        if (lane < NCLASS) {
            float o = p.lb[lane];
            #pragma unroll 4
            for (int k = 0; k < NHID; ++k)
                o = fmaf(hs[w * 64 + k], p.lw[k * NCLASS + lane], o);
            float m = fmaxf(o, __shfl_xor(o, 1));
            m = fmaxf(m, __shfl_xor(m, 2));
            const float ex = __expf(o - m);
            float ss = ex + __shfl_xor(ex, 1);
            ss += __shfl_xor(ss, 2);
            p.out[i * NCLASS + lane] = o - m - __logf(ss);
        }
        __syncthreads();
    }
}

__global__ __launch_bounds__(256, 4) void k_fused(Params p) {
    __shared__ float smem[1024];   // xw partials (4 KB); hs reuses first 256
    const int tid = threadIdx.x;
    const int w = tid >> 6, lane = tid & 63;
    const int gtid = blockIdx.x * 256 + tid;
    const int nthreads = gridDim.x * 256;

    scan_phase(p, gtid, nthreads);
    xw_phase(p, smem, w, lane);
    grid_barrier(p.bar_cnt, p.bar_gen, 1);

    layer_phase(p, p.bufA, p.bufB, p.b1, p.W2, 1, smem, w, lane);
    grid_barrier(p.bar_cnt, p.bar_gen, 2);

    layer_phase(p, p.bufB, p.bufA, p.b2, p.W3, 1, smem, w, lane);
    grid_barrier(p.bar_cnt, p.bar_gen, 3);

    final_phase(p, p.bufA, smem, w, lane);
}

extern "C" void kernel_launch(void* const* d_in, const int* in_sizes, int n_in,
                              void* d_out, int out_size, void* d_ws, size_t ws_size,
                              hipStream_t stream) {
    Params prm;
    prm.x   = (const float*)d_in[0];   // 4096 x 512
    prm.adj = (const float*)d_in[1];   // 4096 x 4096
    prm.P   = (const float*)d_in[2];   // 8390656
    prm.W1  = (const float*)d_in[3];   // 512 x 60
    prm.b1  = (const float*)d_in[4];
    prm.W2  = (const float*)d_in[5];   // 60 x 60
    prm.b2  = (const float*)d_in[6];
    prm.W3  = (const float*)d_in[7];   // 60 x 60
    prm.b3  = (const float*)d_in[8];
    prm.lw  = (const float*)d_in[9];   // 60 x 4
    prm.lb  = (const float*)d_in[10];
    prm.out = (float*)d_out;           // 4096 x 4

    char* ws = (char*)d_ws;
    prm.dcol    = (float*)(ws);                 // 16 KiB (zeroed)
    prm.cnt     = (int*)(ws + 16384);           // 16 KiB (zeroed)
    prm.bar_cnt = (int*)(ws + 32768);           // barrier state (zeroed)
    prm.bar_gen = (int*)(ws + 32768 + 64);
    prm.cols = (int*)(ws + 33792);                              // 1.5 MiB
    prm.vals = (float*)(ws + 33792 + 1572864);                  // 1.5 MiB
    prm.bufA = (float*)(ws + 33792 + 2 * 1572864);              // 1 MiB
    prm.bufB = (float*)(ws + 33792 + 2 * 1572864 + 1048576);    // 1 MiB

    hipMemsetAsync(ws, 0, 33792, stream);   // zero dcol + cnt + barrier state

    int dev = 0, numCU = 256, q = 0;
    hipGetDevice(&dev);
    hipDeviceGetAttribute(&numCU, hipDeviceAttributeMultiprocessorCount, dev);
    if (hipOccupancyMaxActiveBlocksPerMultiprocessor(&q, k_fused, 256, 0) != hipSuccess || q <= 0)
        q = 4;
    int nblk = numCU * q;
    if (nblk > NN / 4) nblk = NN / 4;

    void* kp[] = { (void*)&prm };
    hipLaunchCooperativeKernel((void*)k_fused, dim3(nblk), dim3(256), kp, 0, stream);
}

// Round 4
// 189.234 us; speedup vs baseline: 3.0403x; 2.6526x over previous
//
#include <hip/hip_runtime.h>
#include <math.h>

#define NN 4096
#define NFEAT 512
#define NHID 60
#define NCLASS 4
#define CAP 96      // per-row nnz capacity (mean ~8.2, statistical max ~22)
#define GSTRIDE 64  // padded hidden-state row stride

// ---- scan sub_adj -> per-row lists + column sums --------------------------
// 16384 blocks x 256 threads, one float4 per thread: max waves, max MLP.
__global__ __launch_bounds__(256) void k_scan(const float* __restrict__ adj,
                                              const float* __restrict__ P,
                                              float* __restrict__ dcol,
                                              int* __restrict__ cnt,
                                              int* __restrict__ cols,
                                              float* __restrict__ vals) {
    const int v = blockIdx.x * 256 + threadIdx.x;     // float4 index
    const float4 a = ((const float4*)adj)[v];
    // adj elements are 0.0f or 1.0f -> sum is a cheap any-nonzero test
    if (a.x + a.y + a.z + a.w == 0.f) return;
    const float av[4] = {a.x, a.y, a.z, a.w};
    const int e0 = v * 4;
    #pragma unroll
    for (int q = 0; q < 4; ++q) {
        if (av[q] != 0.f) {
            const int e = e0 + q;
            const int i = e >> 12;
            const int j = e & (NN - 1);
            const int hi = i > j ? i : j;
            const int lo = i > j ? j : i;
            const float pv = P[((hi * (hi + 1)) >> 1) + lo];
            const float s = av[q] / (1.f + __expf(-pv));   // sigmoid(P) * adj
            atomicAdd(&dcol[j], s);
            const int pos = atomicAdd(&cnt[i], 1);
            if (pos < CAP) { cols[i * CAP + pos] = j; vals[i * CAP + pos] = s; }
        }
    }
}

// ---- G1 = x @ W1 (4096x512 @ 512x60): 4 rows/block, K split over 4 waves --
__global__ __launch_bounds__(256) void k_xw(const float* __restrict__ x,
                                            const float* __restrict__ W1,
                                            float* __restrict__ g1) {
    __shared__ float part[1024];
    const int tid = threadIdx.x;
    const int w = tid >> 6, lane = tid & 63;
    const int c = lane < NHID ? lane : 0;
    const int row0 = blockIdx.x * 4;
    const int k0 = w * (NFEAT / 4);
    const float* x0 = x + (row0 + 0) * NFEAT;
    const float* x1 = x + (row0 + 1) * NFEAT;
    const float* x2 = x + (row0 + 2) * NFEAT;
    const float* x3 = x + (row0 + 3) * NFEAT;
    float a0 = 0.f, a1 = 0.f, a2 = 0.f, a3 = 0.f;
    for (int k = k0; k < k0 + NFEAT / 4; k += 4) {
        const float4 xv0 = *(const float4*)(x0 + k);   // wave-uniform 16B
        const float4 xv1 = *(const float4*)(x1 + k);
        const float4 xv2 = *(const float4*)(x2 + k);
        const float4 xv3 = *(const float4*)(x3 + k);
        const float w0 = W1[(k + 0) * NHID + c];       // lane-varying, L2-hot
        const float w1 = W1[(k + 1) * NHID + c];
        const float w2 = W1[(k + 2) * NHID + c];
        const float w3 = W1[(k + 3) * NHID + c];
        a0 = fmaf(xv0.x, w0, fmaf(xv0.y, w1, fmaf(xv0.z, w2, fmaf(xv0.w, w3, a0))));
        a1 = fmaf(xv1.x, w0, fmaf(xv1.y, w1, fmaf(xv1.z, w2, fmaf(xv1.w, w3, a1))));
        a2 = fmaf(xv2.x, w0, fmaf(xv2.y, w1, fmaf(xv2.z, w2, fmaf(xv2.w, w3, a2))));
        a3 = fmaf(xv3.x, w0, fmaf(xv3.y, w1, fmaf(xv3.z, w2, fmaf(xv3.w, w3, a3))));
    }
    part[(w * 4 + 0) * 64 + lane] = a0;
    part[(w * 4 + 1) * 64 + lane] = a1;
    part[(w * 4 + 2) * 64 + lane] = a2;
    part[(w * 4 + 3) * 64 + lane] = a3;
    __syncthreads();
    // wave w reduces row w across the 4 K-slices
    const float o = part[(0 * 4 + w) * 64 + lane] + part[(1 * 4 + w) * 64 + lane]
                  + part[(2 * 4 + w) * 64 + lane] + part[(3 * 4 + w) * 64 + lane];
    g1[(row0 + w) * GSTRIDE + lane] = (lane < NHID) ? o : 0.f;
}

// ---- spmm edge accumulation, 4-batched for MLP ----------------------------
__device__ __forceinline__ float spmm_row(const float* __restrict__ gin,
                                          const float* __restrict__ dcol,
                                          const int* __restrict__ cnt,
                                          const int* __restrict__ cols,
                                          const float* __restrict__ vals,
                                          int i, int lane, float di) {
    const int nn = min(cnt[i], CAP);
    float acc = gin[i * GSTRIDE + lane] * di;   // self-loop term
    const int4*   c4 = (const int4*)(cols + i * CAP);
    const float4* v4 = (const float4*)(vals + i * CAP);
    int e = 0;
    for (; e + 4 <= nn; e += 4) {
        const int4   jj = c4[e >> 2];
        const float4 vv = v4[e >> 2];
        const float f0 = vv.x * rsqrtf(1.f + dcol[jj.x]);
        const float f1 = vv.y * rsqrtf(1.f + dcol[jj.y]);
        const float f2 = vv.z * rsqrtf(1.f + dcol[jj.z]);
        const float f3 = vv.w * rsqrtf(1.f + dcol[jj.w]);
        const float g0 = gin[jj.x * GSTRIDE + lane];
        const float g1 = gin[jj.y * GSTRIDE + lane];
        const float g2 = gin[jj.z * GSTRIDE + lane];
        const float g3 = gin[jj.w * GSTRIDE + lane];
        acc = fmaf(f0, g0, fmaf(f1, g1, fmaf(f2, g2, fmaf(f3, g3, acc))));
    }
    for (; e < nn; ++e) {
        const int j = cols[i * CAP + e];
        const float f = vals[i * CAP + e] * rsqrtf(1.f + dcol[j]);
        acc = fmaf(f, gin[j * GSTRIDE + lane], acc);
    }
    return acc * di;
}

// ---- h = relu(spmm(gin)+bias); gout = h @ W (60x60). One row per block. ---
__global__ __launch_bounds__(64) void k_layer(const float* __restrict__ gin,
                                              float* __restrict__ gout,
                                              const float* __restrict__ dcol,
                                              const int* __restrict__ cnt,
                                              const int* __restrict__ cols,
                                              const float* __restrict__ vals,
                                              const float* __restrict__ bias,
                                              const float* __restrict__ W) {
    __shared__ float hs[64];
    const int i = blockIdx.x;
    const int lane = threadIdx.x;
    const float di = rsqrtf(1.f + dcol[i]);
    const float acc = spmm_row(gin, dcol, cnt, cols, vals, i, lane, di);
    float hv = 0.f;
    if (lane < NHID) hv = fmaxf(acc + bias[lane], 0.f);
    hs[lane] = hv;
    __syncthreads();
    const int c = lane < NHID ? lane : 0;
    float o = 0.f;
    #pragma unroll 4
    for (int k = 0; k < NHID; ++k)
        o = fmaf(hs[k], W[k * NHID + c], o);   // hs LDS broadcast (conflict-free)
    gout[i * GSTRIDE + lane] = (lane < NHID) ? o : 0.f;
}

// ---- h3 = spmm+b3; logits = h3@lin_w+lin_b; log_softmax over 4 classes ----
__global__ __launch_bounds__(64) void k_final(const float* __restrict__ gin,
                                              float* __restrict__ out,
                                              const float* __restrict__ dcol,
                                              const int* __restrict__ cnt,
                                              const int* __restrict__ cols,
                                              const float* __restrict__ vals,
                                              const float* __restrict__ b3,
                                              const float* __restrict__ lw,
                                              const float* __restrict__ lb) {
    __shared__ float hs[64];
    const int i = blockIdx.x;
    const int lane = threadIdx.x;
    const float di = rsqrtf(1.f + dcol[i]);
    const float acc = spmm_row(gin, dcol, cnt, cols, vals, i, lane, di);
    hs[lane] = (lane < NHID) ? acc + b3[lane] : 0.f;
    __syncthreads();
    if (lane < NCLASS) {
        float o = lb[lane];
        #pragma unroll 4
        for (int k = 0; k < NHID; ++k)
            o = fmaf(hs[k], lw[k * NCLASS + lane], o);
        float m = fmaxf(o, __shfl_xor(o, 1));
        m = fmaxf(m, __shfl_xor(m, 2));
        const float ex = __expf(o - m);
        float ss = ex + __shfl_xor(ex, 1);
        ss += __shfl_xor(ss, 2);
        out[i * NCLASS + lane] = o - m - __logf(ss);
    }
}

extern "C" void kernel_launch(void* const* d_in, const int* in_sizes, int n_in,
                              void* d_out, int out_size, void* d_ws, size_t ws_size,
                              hipStream_t stream) {
    const float* x   = (const float*)d_in[0];   // 4096 x 512
    const float* adj = (const float*)d_in[1];   // 4096 x 4096
    const float* P   = (const float*)d_in[2];   // 8390656
    const float* W1  = (const float*)d_in[3];   // 512 x 60
    const float* b1  = (const float*)d_in[4];
    const float* W2  = (const float*)d_in[5];   // 60 x 60
    const float* b2  = (const float*)d_in[6];
    const float* W3  = (const float*)d_in[7];   // 60 x 60
    const float* b3  = (const float*)d_in[8];
    const float* lw  = (const float*)d_in[9];   // 60 x 4
    const float* lb  = (const float*)d_in[10];
    float* out = (float*)d_out;                 // 4096 x 4

    char* ws = (char*)d_ws;
    float* dcol = (float*)(ws);                 // 16 KiB (zeroed)
    int*   cnt  = (int*)(ws + 16384);           // 16 KiB (zeroed)
    int*   cols = (int*)(ws + 32768);                           // 1.5 MiB
    float* vals = (float*)(ws + 32768 + 1572864);               // 1.5 MiB
    float* bufA = (float*)(ws + 32768 + 2 * 1572864);           // 1 MiB
    float* bufB = (float*)(ws + 32768 + 2 * 1572864 + 1048576); // 1 MiB

    hipMemsetAsync(ws, 0, 32768, stream);       // zero dcol + cnt

    k_scan <<<(NN * NN / 4) / 256, 256, 0, stream>>>(adj, P, dcol, cnt, cols, vals);
    k_xw   <<<NN / 4, 256, 0, stream>>>(x, W1, bufA);
    k_layer<<<NN, 64, 0, stream>>>(bufA, bufB, dcol, cnt, cols, vals, b1, W2);
    k_layer<<<NN, 64, 0, stream>>>(bufB, bufA, dcol, cnt, cols, vals, b2, W3);
    k_final<<<NN, 64, 0, stream>>>(bufA, out, dcol, cnt, cols, vals, b3, lw, lb);
}